// Round 14
// baseline (57.443 us; speedup 1.0000x reference)
//
#include <hip/hip_runtime.h>
#include <stdint.h>
#include <math.h>

// ---------------------------------------------------------------------------
// SparseExplorerRouting, round 17.
//
// Carried facts (best = R16 54.1us; R1-R3/R5/R9-R16 PASSED absmax 0):
//   * jax_threefry_partitionable=True counter scheme; key(42) -> (0,42);
//     walk (v,w) = split child v*5+w; per-step children ctr (0,{0,1,2}).
//   * output int32 {flags[1024], sum_aborts, sum_restarts}.
//   * E-table argmax(E/w) trick, w=-log(u); minE<e^0.5 == min_sim<0.1.
//   * WALK PARKED at R13 paired-prologue (34.7us); all restructures lost.
//   * Band ledger at 19.4us (post R15 f32-dots + R16 K-split/2-blocks-CU):
//     LDS b128 reads dominate -- 68/wave-half because the 2 centers
//     independently re-read 16 shared d-rows; f64 butterfly next item.
//   * PRECISION ball: reference computes dots in f32 (~2e-6 own noise);
//     R15's f32 partials (worst ~2.5e-7 on s) proven safe on HW.
//
// Round 17 changes (band dot phase only; walk = R13 verbatim):
//   * SHARED-ROW d-loop: rows cl0+1..cl0+17 read ONCE per wave-half and
//     consumed by both centers (static predicates: center0 r<=16,
//     center1 r>=2). 68 -> 38 b128 reads per wave-half (-44%).
//   * f32 butterfly + f32 p0/p1: 6-stage tree in f32 (~1e-7 RMS on s,
//     same ball as R15's proven worst case; 10x below reference noise).
//     sumsq stays f64; dsum accumulation stays f64.
// ---------------------------------------------------------------------------

#define HID        1024
#define NUM_WALKS  5
#define WALK_LEN   8
#define HALF_WIN   16
#define E_THRESH   1.6487212707001282   // exp(0.5) = exp(5 * BIRTH_DEATH_EPS)

#define CENTERS    16                   // centers per band block
#define SROWS      32                   // staged rows = CENTERS + 16 halo
#define KHALF      512                  // staged columns per pass

__device__ __forceinline__ void tf2x32(uint32_t k0, uint32_t k1,
                                       uint32_t& x0, uint32_t& x1) {
  uint32_t ks2 = k0 ^ k1 ^ 0x1BD11BDAu;
  x0 += k0; x1 += k1;
#define TFR(r) { x0 += x1; x1 = (x1 << (r)) | (x1 >> (32 - (r))); x1 ^= x0; }
  TFR(13) TFR(15) TFR(26) TFR(6)
  x0 += k1;  x1 += ks2 + 1u;
  TFR(17) TFR(29) TFR(16) TFR(24)
  x0 += ks2; x1 += k0 + 2u;
  TFR(13) TFR(15) TFR(26) TFR(6)
  x0 += k0;  x1 += k1 + 3u;
  TFR(17) TFR(29) TFR(16) TFR(24)
  x0 += k1;  x1 += ks2 + 4u;
  TFR(13) TFR(15) TFR(26) TFR(6)
  x0 += ks2; x1 += k0 + 5u;
#undef TFR
}

__device__ __forceinline__ uint32_t tf_fold(uint32_t k0, uint32_t k1,
                                            uint32_t c0, uint32_t c1) {
  tf2x32(k0, k1, c0, c1);
  return c0 ^ c1;
}

// w = -log(u), u = k*2^-23 (k = bits>>9), via HW v_log_f32.
// Proven safe on HW (R12-R16 absmax 0).
__device__ __forceinline__ double fast_neg_log(uint32_t bits) {
  const uint32_t k = bits >> 9;
  if (k == 0) return 87.33654475055310899;    // -log(2^-126) clamp
  const float u  = (float)k * 1.1920928955078125e-7f;   // k * 2^-23, exact
  const float l2 = __log2f(u);                          // v_log_f32
  return (double)l2 * -0.6931471805599453;
}

// 16-value f32 reduce-scatter butterfly: value bit3..0 <- lane bit5..2.
// Returns the reduced value owned by this lane (valid at (lane&3)==0).
__device__ __forceinline__ float reduce16_f32(float (&p)[16], int lane) {
#pragma unroll
  for (int v = 0; v < 8; ++v) {                     // stage xor 32
    float send = (lane & 32) ? p[v] : p[v+8];
    float recv = __shfl_xor(send, 32);
    float mine = (lane & 32) ? p[v+8] : p[v];
    p[v] = mine + recv;
  }
#pragma unroll
  for (int v = 0; v < 4; ++v) {                     // stage xor 16
    float send = (lane & 16) ? p[v] : p[v+4];
    float recv = __shfl_xor(send, 16);
    float mine = (lane & 16) ? p[v+4] : p[v];
    p[v] = mine + recv;
  }
#pragma unroll
  for (int v = 0; v < 2; ++v) {                     // stage xor 8
    float send = (lane & 8) ? p[v] : p[v+2];
    float recv = __shfl_xor(send, 8);
    float mine = (lane & 8) ? p[v+2] : p[v];
    p[v] = mine + recv;
  }
  {                                                 // stage xor 4
    float send = (lane & 4) ? p[0] : p[1];
    float recv = __shfl_xor(send, 4);
    float mine = (lane & 4) ? p[1] : p[0];
    p[0] = mine + recv;
  }
  p[0] += __shfl_xor(p[0], 2);                      // stage xor 2
  p[0] += __shfl_xor(p[0], 1);                      // stage xor 1
  return p[0];
}

// ---- fused band + rowsq + d_out zeroing; shared-row f32 dots ---------------
__global__ __launch_bounds__(512) void band_fused_kernel(
    const float* __restrict__ H, double* __restrict__ sumsq,
    double* __restrict__ E, int* __restrict__ out, int out_n, int seq_len) {
  __shared__ __align__(16) float  tile[SROWS][KHALF];   // 64 KB
  __shared__ double ssq[SROWS];

  if (blockIdx.x == 0) {                 // fold d_out zeroing in (dispatch
    for (int t = threadIdx.x; t < out_n; t += 512) out[t] = 0;   // ordering
  }                                      // guarantees walk sees zeros)

  int wg = blockIdx.x;
  {
    const int nwg = gridDim.x;           // bijective XCD swizzle (nwg%8==0)
    if ((nwg & 7) == 0) wg = (wg & 7) * (nwg >> 3) + (wg >> 3);
  }
  const int wid  = (int)(threadIdx.x >> 6);   // 0..7
  const int lane = (int)(threadIdx.x & 63);
  const int i0   = wg * CENTERS;
  const float4* __restrict__ H4 = (const float4*)H;

  double acc[4]  = {0.0, 0.0, 0.0, 0.0};   // per staged row, across halves
  double dsum[2] = {0.0, 0.0};             // per-cc owner-lane band sums

#pragma unroll
  for (int half = 0; half < 2; ++half) {
    // ---- stage 4 rows per wave, cols [half*512, half*512+512) ----
    // sumsq per-lane accumulation order k0..k3 preserved across halves
    // (bit-identical to R5/R15/R16's order; f64, proven).
#pragma unroll
    for (int rr = 0; rr < 4; ++rr) {
      const int local = wid * 4 + rr;    // wave-uniform
      const int row   = i0 + local;
      if (row < seq_len) {
        const float4* src = H4 + ((size_t)row << 8);
        float4* dst = (float4*)&tile[local][0];
#pragma unroll
        for (int kk = 0; kk < 2; ++kk) { // global chunk k = 2*half + kk
          float4 x = src[lane + ((half * 2 + kk) << 6)];
          dst[lane + (kk << 6)] = x;
          acc[rr] += (double)x.x * x.x + (double)x.y * x.y
                   + (double)x.z * x.z + (double)x.w * x.w;
        }
      }
    }
    if (half == 1) {                     // finalize sumsq: one butterfly
#pragma unroll
      for (int rr = 0; rr < 4; ++rr) {
        const int local = wid * 4 + rr;
        const int row   = i0 + local;
        if (row < seq_len) {
          double a = acc[rr];
#pragma unroll
          for (int off = 32; off; off >>= 1) a += __shfl_xor(a, off);
          if (lane == 0) {
            ssq[local] = a;
            if (local < CENTERS) sumsq[row] = a;  // row owned by 1 block
          }
        }
      }
    }
    __syncthreads();

    // ---- SHARED-ROW dots: 2 centers per wave, rows read once ----
    {
      const int cl0 = wid * 2;           // centers cl0, cl0+1 (0..15)
      const int iA  = i0 + cl0;
      const int iB  = iA + 1;

      float a0[8], a1[8];
      {
        const float4* rc = (const float4*)&tile[cl0][0];
#pragma unroll
        for (int kk = 0; kk < 2; ++kk) {
          float4 x = rc[lane + (kk << 6)];
          a0[4*kk+0] = x.x; a0[4*kk+1] = x.y;
          a0[4*kk+2] = x.z; a0[4*kk+3] = x.w;
        }
        const float4* rd = (const float4*)&tile[cl0 + 1][0];
#pragma unroll
        for (int kk = 0; kk < 2; ++kk) {
          float4 x = rd[lane + (kk << 6)];
          a1[4*kk+0] = x.x; a1[4*kk+1] = x.y;
          a1[4*kk+2] = x.z; a1[4*kk+3] = x.w;
        }
      }

      float p0[16], p1[16];
#pragma unroll
      for (int d = 0; d < 16; ++d) { p0[d] = 0.0f; p1[d] = 0.0f; }

      // rows cl0+1 .. cl0+17 (max 15+17=32? cl0<=14 -> <=31, in tile).
      // center0 (iA) uses r = 1..16 (d = r); center1 (iB) uses r = 2..17
      // (d = r-1). Static predicates after unroll. Per-lane dot order
      // matches R15/R16 (kk-major, xyzw within).
#pragma unroll
      for (int r = 1; r <= 17; ++r) {
        const float4* rb = (const float4*)&tile[cl0 + r][0];
        const float4 x0 = rb[lane];
        const float4 x1 = rb[lane + 64];
        if (r <= 16) {
          float ps = 0.0f;
          ps += a0[0] * x0.x + a0[1] * x0.y + a0[2] * x0.z + a0[3] * x0.w;
          ps += a0[4] * x1.x + a0[5] * x1.y + a0[6] * x1.z + a0[7] * x1.w;
          p0[r-1] += ps;
        }
        if (r >= 2) {
          float ps = 0.0f;
          ps += a1[0] * x0.x + a1[1] * x0.y + a1[2] * x0.z + a1[3] * x0.w;
          ps += a1[4] * x1.x + a1[5] * x1.y + a1[6] * x1.z + a1[7] * x1.w;
          p1[r-2] += ps;
        }
      }

      // f32 reduce-scatter butterflies; accumulate halves in f64.
      if (iA < seq_len) {
        const float r0 = reduce16_f32(p0, lane);
        dsum[0] += (double)r0;
      }
      if (iB < seq_len) {
        const float r1 = reduce16_f32(p1, lane);
        dsum[1] += (double)r1;
      }
    }
    __syncthreads();                     // compute done before re-stage
  }

  // ---- epilogue: lane owns d = v+1 for its cc centers ----
  const int v = ((lane >> 2) & 1) | (((lane >> 3) & 1) << 1)
              | (((lane >> 4) & 1) << 2) | (((lane >> 5) & 1) << 3);
  const int d = v + 1;
#pragma unroll
  for (int cc = 0; cc < 2; ++cc) {
    const int cl = wid * 2 + cc;
    const int i  = i0 + cl;
    if (i < seq_len && (lane & 3) == 0 && i + d < seq_len) {
      const double ni = sqrt(ssq[cl]) + 1e-8;
      const double s  = dsum[cc] / (ni * (sqrt(ssq[cl + d]) + 1e-8));
      const double Ev = exp(5.0 * s);
      E[(size_t)i * 33 + 16 + d]       = Ev;
      E[(size_t)(i + d) * 33 + 16 - d] = Ev;
    }
  }
}

// ---- per-row sum of squares (f64) + d_out zeroing (fallback tier only) -----
__global__ __launch_bounds__(256) void rowsq_kernel(
    const float* __restrict__ H, double* __restrict__ sumsq,
    int* __restrict__ out, int out_n, int seq_len) {
  if (blockIdx.x == 0) {
    for (int t = threadIdx.x; t < out_n; t += 256) out[t] = 0;
  }
  const int row  = (int)((blockIdx.x * blockDim.x + threadIdx.x) >> 6);
  const int lane = threadIdx.x & 63;
  if (row >= seq_len) return;
  const float4* r = (const float4*)(H + (size_t)row * HID);
  double acc = 0.0;
#pragma unroll
  for (int k = 0; k < 4; ++k) {
    float4 x = r[lane + (k << 6)];
    acc += (double)x.x * x.x + (double)x.y * x.y
         + (double)x.z * x.z + (double)x.w * x.w;
  }
#pragma unroll
  for (int off = 32; off; off >>= 1) acc += __shfl_xor(acc, off);
  if (lane == 0) sumsq[row] = acc;
}

// ---- walk kernel: R13 step-paired prologue, unrolled steps (VERBATIM) ------
__global__ __launch_bounds__(256) void walk_pre_kernel(
    const double* __restrict__ E, const double* __restrict__ sumsq,
    const int* __restrict__ viol, int* __restrict__ out,
    int nv, int seq_len) {
  int wave = (int)((blockIdx.x * blockDim.x + threadIdx.x) >> 6);
  const int lane = threadIdx.x & 63;
  if (wave >= nv * NUM_WALKS) return;
  wave = __builtin_amdgcn_readfirstlane(wave);
  const int v     = wave / NUM_WALKS;
  const int start = viol[v];

  uint32_t key0 = 0u, key1 = (uint32_t)wave;
  tf2x32(0u, 42u, key0, key1);
  key0 = __builtin_amdgcn_readfirstlane(key0);
  key1 = __builtin_amdgcn_readfirstlane(key1);

  // ---- key chain (wave-uniform SALU, saved for cold paths) ----
  uint32_t k0s[WALK_LEN], k1s[WALK_LEN];
#pragma unroll
  for (int s = 0; s < WALK_LEN; ++s) {
    k0s[s] = key0; k1s[s] = key1;
    uint32_t nk0 = 0u, nk1 = 0u; tf2x32(key0, key1, nk0, nk1);
    key0 = __builtin_amdgcn_readfirstlane(nk0);
    key1 = __builtin_amdgcn_readfirstlane(nk1);
  }

  // ---- STEP-PAIRED prologue: 4 per-lane folds produce all 8 steps' w ----
  const int  sl_mine = lane & 31;
  const uint32_t jpk = (uint32_t)(sl_mine + (sl_mine > 15 ? 1 : 0));
  double invwp[WALK_LEN / 2];
#pragma unroll
  for (int t = 0; t < WALK_LEN / 2; ++t) {
    uint32_t ksA0 = 0u, ksA1 = 1u; tf2x32(k0s[2*t],   k1s[2*t],   ksA0, ksA1);
    uint32_t sA0  = 0u, sA1  = 0u; tf2x32(ksA0, ksA1, sA0, sA1);   // at=0
    uint32_t ksB0 = 0u, ksB1 = 1u; tf2x32(k0s[2*t+1], k1s[2*t+1], ksB0, ksB1);
    uint32_t sB0  = 0u, sB1  = 0u; tf2x32(ksB0, ksB1, sB0, sB1);   // at=0
    const uint32_t s0 = (lane & 32) ? sB0 : sA0;   // 2-op per-lane select
    const uint32_t s1 = (lane & 32) ? sB1 : sA1;
    const uint32_t bits = tf_fold(s0, s1, 0u, jpk);
    invwp[t] = 1.0 / fast_neg_log(bits);
  }

  // consuming lane j reads slot sl = j - (j>16) from half (step&1)
  const int sl_use = (lane < 33 && lane != HALF_WIN)
                   ? (lane - (lane > HALF_WIN)) : 0;

  int    cur = start, prev = start, plen = 1;
  double minE = 1e300;
  bool   detected = false;
  int    aborts = 0, restarts = 0;
  // carried |h|^2 of prev / cur (identical doubles to sumsq[] entries)
  double na_d = sumsq[start], nb_d = na_d;

#pragma unroll
  for (int step = 0; step < WALK_LEN; ++step) {
    const int  myidx   = cur - HALF_WIN + lane;
    const bool myvalid = (lane < 33) && (lane != HALF_WIN) &&
                         (myidx >= 0) && (myidx < seq_len);
    const int  clipped = myidx < 0 ? 0 : (myidx >= seq_len ? seq_len - 1 : myidx);
    const double Ej = E[(size_t)cur * 33 + (lane < 33 ? lane : 0)];
    const double sq_win = sumsq[clipped];   // window |h|^2, issued with Ej
    // my step's 1/w: one bpermute from the paired prologue value
    const double invw_s = __shfl(invwp[step >> 1],
                                 ((step & 1) << 5) + sl_use);

    bool found = false; int fails = 0, p = 0, cand = 0;
    double nc_d = 0.0;
    for (int at = 0; at < 3; ++at) {
      double f; int bi;
      if (myvalid) {
        if (at == 0) {
          f = Ej * invw_s;      // hot path: no threefry, no log, no div
        } else {                // cold path (rare): recompute from saved key
          uint32_t ks0 = 0u, ks1 = 1u; tf2x32(k0s[step], k1s[step], ks0, ks1);
          uint32_t s0 = 0u, s1 = (uint32_t)at; tf2x32(ks0, ks1, s0, s1);
          const uint32_t bits = tf_fold(s0, s1, 0u, (uint32_t)lane);
          f = Ej / fast_neg_log(bits);
        }
        bi = lane;
      } else { f = -1.0; bi = 1000; }
#pragma unroll
      for (int off = 32; off; off >>= 1) {
        const double of = __shfl_xor(f, off);
        const int    oi = __shfl_xor(bi, off);
        if (of > f || (of == f && oi < bi)) { f = of; bi = oi; }
      }
      p    = bi;
      cand = cur - HALF_WIN + p;
      nc_d = __shfl(sq_win, p);     // == sumsq[cand], no dependent load
      bool ok;
      if (plen < 2) ok = true;
      else {
        const float na = (float)na_d, nb = (float)nb_d, nc = (float)nc_d;
        const float tr  = (na * nb * nc) /
                          ((na + 1e-8f) * (nb + 1e-8f) * (nc + 1e-8f));
        const float dev = fabsf(tr - rintf(tr));
        ok = (dev <= 0.1f) && (tr <= 1.5f);
      }
      if (ok) { found = true; break; }
      ++fails;
    }
    aborts += fails;

    if (found) {
      const double Ewin = __shfl(Ej, p);
      minE = fmin(minE, Ewin);
      const bool closed = (cand == start) && (plen > 2);
      prev = cur; cur = cand; plen += 1;
      na_d = nb_d; nb_d = nc_d;
      if (closed) { if (minE < E_THRESH) detected = true; break; }
    } else {
      ++restarts;                 // rare path: restart chain from saved key
      uint32_t kr0 = 0u, kr1 = 2u; tf2x32(k0s[step], k1s[step], kr0, kr1);
      uint32_t h0 = 0u, h1 = 0u; tf2x32(kr0, kr1, h0, h1);
      uint32_t l0 = 0u, l1 = 1u; tf2x32(kr0, kr1, l0, l1);
      const uint32_t hi = tf_fold(h0, h1, 0u, 0u);
      const uint32_t lo = tf_fold(l0, l1, 0u, 0u);
      const uint32_t span = (uint32_t)nv;
      uint32_t mult = (65536u % span); mult = (mult * mult) % span;
      const uint32_t r = ((hi % span) * mult + (lo % span)) % span;
      const int node = viol[r];
      cur = node; prev = node; plen = 1;
      na_d = sumsq[node]; nb_d = na_d;
    }
  }

  if (lane == 0) {
    if (detected)      atomicOr(&out[v], 1);
    if (aborts != 0)   atomicAdd(&out[nv], aborts);
    if (restarts != 0) atomicAdd(&out[nv + 1], restarts);
  }
}

// ---- fallback: round-1 in-walk dot kernel (only if ws too small) -----------
__global__ __launch_bounds__(256) void walk_ref_kernel(
    const float* __restrict__ H, const int* __restrict__ viol,
    const double* __restrict__ sumsq, int* __restrict__ out,
    int nv, int seq_len) {
  const int wave = (int)((blockIdx.x * blockDim.x + threadIdx.x) >> 6);
  const int lane = threadIdx.x & 63;
  if (wave >= nv * NUM_WALKS) return;
  const int v     = wave / NUM_WALKS;
  const int start = viol[v];
  uint32_t key0 = 0u, key1 = (uint32_t)wave;
  tf2x32(0u, 42u, key0, key1);
  const float4* __restrict__ H4 = (const float4*)H;
  int    cur = start, prev = start, plen = 1;
  double min_sim = 1e9;
  bool   detected = false;
  int    aborts = 0, restarts = 0;
  for (int step = 0; step < WALK_LEN; ++step) {
    uint32_t nk0 = 0u, nk1 = 0u; tf2x32(key0, key1, nk0, nk1);
    uint32_t ks0 = 0u, ks1 = 1u; tf2x32(key0, key1, ks0, ks1);
    uint32_t kr0 = 0u, kr1 = 2u; tf2x32(key0, key1, kr0, kr1);
    const double ncur = sqrt(sumsq[cur]) + 1e-8;
    double a[16];
    {
      const float4* rc = H4 + ((size_t)cur << 8);
#pragma unroll
      for (int k = 0; k < 4; ++k) {
        float4 x = rc[lane + (k << 6)];
        a[4*k+0] = x.x; a[4*k+1] = x.y; a[4*k+2] = x.z; a[4*k+3] = x.w;
      }
    }
    double my_sim = 0.0;
    for (int jj = 0; jj < 33; ++jj) {
      const int idx = cur - HALF_WIN + jj;
      if (jj == HALF_WIN || idx < 0 || idx >= seq_len) continue;
      const float4* rb = H4 + ((size_t)idx << 8);
      double acc = 0.0;
#pragma unroll
      for (int k = 0; k < 4; ++k) {
        float4 x = rb[lane + (k << 6)];
        acc += a[4*k+0] * (double)x.x + a[4*k+1] * (double)x.y
             + a[4*k+2] * (double)x.z + a[4*k+3] * (double)x.w;
      }
#pragma unroll
      for (int off = 32; off; off >>= 1) acc += __shfl_xor(acc, off);
      const double s = acc / (ncur * (sqrt(sumsq[idx]) + 1e-8));
      if (lane == jj) my_sim = s;
    }
    bool found = false; int fails = 0, p = 0, cand = 0;
    const int  myidx   = cur - HALF_WIN + lane;
    const bool myvalid = (lane < 33) && (lane != HALF_WIN) &&
                         (myidx >= 0) && (myidx < seq_len);
    for (int at = 0; at < 3; ++at) {
      uint32_t s0 = 0u, s1 = (uint32_t)at; tf2x32(ks0, ks1, s0, s1);
      double z; int bi;
      if (myvalid) {
        const uint32_t bits = tf_fold(s0, s1, 0u, (uint32_t)lane);
        const uint32_t fb   = (bits >> 9) | 0x3f800000u;
        const float    f    = __uint_as_float(fb) - 1.0f;
        const float    u    = (f > 0.0f) ? f : 1.1754943508222875e-38f;
        const double   g    = -log(-log((double)u));
        z  = g + 5.0 * my_sim;
        bi = lane;
      } else { z = -1e300; bi = 1000; }
#pragma unroll
      for (int off = 32; off; off >>= 1) {
        const double oz = __shfl_xor(z, off);
        const int    oi = __shfl_xor(bi, off);
        if (oz > z || (oz == z && oi < bi)) { z = oz; bi = oi; }
      }
      p    = bi;
      cand = cur - HALF_WIN + p;
      bool ok;
      if (plen < 2) ok = true;
      else {
        const float na = (float)sumsq[prev], nb = (float)sumsq[cur],
                    nc = (float)sumsq[cand];
        const float tr  = (na * nb * nc) /
                          ((na + 1e-8f) * (nb + 1e-8f) * (nc + 1e-8f));
        const float dev = fabsf(tr - rintf(tr));
        ok = (dev <= 0.1f) && (tr <= 1.5f);
      }
      if (ok) { found = true; break; }
      ++fails;
    }
    aborts += fails;
    if (found) {
      const double sim = __shfl(my_sim, p);
      const double nm  = fmin(min_sim, sim);
      const bool closed = (cand == start) && (plen > 2);
      prev = cur; cur = cand; plen += 1; min_sim = nm;
      if (closed) { if (nm < 0.1) detected = true; break; }
    } else {
      ++restarts;
      uint32_t h0 = 0u, h1 = 0u; tf2x32(kr0, kr1, h0, h1);
      uint32_t l0 = 0u, l1 = 1u; tf2x32(kr0, kr1, l0, l1);
      const uint32_t hi = tf_fold(h0, h1, 0u, 0u);
      const uint32_t lo = tf_fold(l0, l1, 0u, 0u);
      const uint32_t span = (uint32_t)nv;
      uint32_t mult = (65536u % span); mult = (mult * mult) % span;
      const uint32_t r = ((hi % span) * mult + (lo % span)) % span;
      const int node = viol[r];
      cur = node; prev = node; plen = 1;
    }
    key0 = nk0; key1 = nk1;
  }
  if (lane == 0) {
    if (detected)      atomicOr(&out[v], 1);
    if (aborts != 0)   atomicAdd(&out[nv], aborts);
    if (restarts != 0) atomicAdd(&out[nv + 1], restarts);
  }
}

extern "C" void kernel_launch(void* const* d_in, const int* in_sizes, int n_in,
                              void* d_out, int out_size, void* d_ws, size_t ws_size,
                              hipStream_t stream) {
  const float* H    = (const float*)d_in[0];
  const int*   viol = (const int*)d_in[1];
  const int    nv      = in_sizes[1];
  const int    seq_len = in_sizes[0] / HID;
  const int    nwalks  = nv * NUM_WALKS;

  double* sumsq = (double*)d_ws;                       // seq_len * 8 B
  double* Etab  = (double*)((char*)d_ws + (size_t)seq_len * sizeof(double));
  const size_t need = (size_t)seq_len * sizeof(double)
                    + (size_t)seq_len * 33 * sizeof(double);

  const int wblocks = (nwalks + 3) / 4;

  if (ws_size >= need) {
    const int blocks = (seq_len + CENTERS - 1) / CENTERS;   // 512 @ 8192
    band_fused_kernel<<<blocks, 512, 0, stream>>>(H, sumsq, Etab,
                                                  (int*)d_out, out_size,
                                                  seq_len);
    walk_pre_kernel<<<wblocks, 256, 0, stream>>>(Etab, sumsq, viol,
                                                 (int*)d_out, nv, seq_len);
  } else {
    const int blocks = (seq_len + 3) / 4;
    rowsq_kernel<<<blocks, 256, 0, stream>>>(H, sumsq, (int*)d_out,
                                             out_size, seq_len);
    walk_ref_kernel<<<wblocks, 256, 0, stream>>>(H, viol, sumsq,
                                                 (int*)d_out, nv, seq_len);
  }
}

// Round 15
// 53.286 us; speedup vs baseline: 1.0780x; 1.0780x over previous
//
#include <hip/hip_runtime.h>
#include <stdint.h>
#include <math.h>

// ---------------------------------------------------------------------------
// SparseExplorerRouting, round 18.
//
// Carried facts (best = R16 54.1us; R1-R3/R5/R9-R17 PASSED absmax 0):
//   * jax_threefry_partitionable=True counter scheme; key(42) -> (0,42);
//     walk (v,w) = split child v*5+w; per-step children ctr (0,{0,1,2}).
//   * output int32 {flags[1024], sum_aborts, sum_restarts}.
//   * E-table argmax(E/w) trick, w=-log(u); minE<e^0.5 == min_sim<0.1.
//   * WALK PARKED structurally at R13 paired-prologue; band at R16
//     K-split + f32 partial dots (proven 54.1).
//   * R17 lesson: shared-row + f32 butterfly in band REGRESSED (+3.3) --
//     LDS-read cycle models unreliable; only f32/f64 PIPE-RATE predictions
//     have held (R15 matched; R16 partial).
//   * PRECISION: reference's own categorical argmax is f32 (f32 logits +
//     f32 gumbel); our f64 pick passed 13x => pick margins tolerate >=1e-7.
//     v_log_f32 (6e-8) proven safe R12-R17.
//
// Round 18 change (walk argmax value path only; band = R16 VERBATIM):
//   * f32 pick value: f = (float)Ej * invwf (f32), butterfly on f32 --
//     shfl b32 (1 instr vs 2 for f64) and 2-cy compares; 6 stages x 3
//     attempts x 8 steps. minE path unchanged: Ewin = shfl(f64 Ej, p).
//     Cold paths compute f64 then cast (same comparison domain).
// ---------------------------------------------------------------------------

#define HID        1024
#define NUM_WALKS  5
#define WALK_LEN   8
#define HALF_WIN   16
#define E_THRESH   1.6487212707001282   // exp(0.5) = exp(5 * BIRTH_DEATH_EPS)

#define CENTERS    16                   // centers per band block
#define SROWS      32                   // staged rows = CENTERS + 16 halo
#define KHALF      512                  // staged columns per pass

__device__ __forceinline__ void tf2x32(uint32_t k0, uint32_t k1,
                                       uint32_t& x0, uint32_t& x1) {
  uint32_t ks2 = k0 ^ k1 ^ 0x1BD11BDAu;
  x0 += k0; x1 += k1;
#define TFR(r) { x0 += x1; x1 = (x1 << (r)) | (x1 >> (32 - (r))); x1 ^= x0; }
  TFR(13) TFR(15) TFR(26) TFR(6)
  x0 += k1;  x1 += ks2 + 1u;
  TFR(17) TFR(29) TFR(16) TFR(24)
  x0 += ks2; x1 += k0 + 2u;
  TFR(13) TFR(15) TFR(26) TFR(6)
  x0 += k0;  x1 += k1 + 3u;
  TFR(17) TFR(29) TFR(16) TFR(24)
  x0 += k1;  x1 += ks2 + 4u;
  TFR(13) TFR(15) TFR(26) TFR(6)
  x0 += ks2; x1 += k0 + 5u;
#undef TFR
}

__device__ __forceinline__ uint32_t tf_fold(uint32_t k0, uint32_t k1,
                                            uint32_t c0, uint32_t c1) {
  tf2x32(k0, k1, c0, c1);
  return c0 ^ c1;
}

// w = -log(u), u = k*2^-23 (k = bits>>9), via HW v_log_f32.
// Proven safe on HW (R12-R17 absmax 0).
__device__ __forceinline__ double fast_neg_log(uint32_t bits) {
  const uint32_t k = bits >> 9;
  if (k == 0) return 87.33654475055310899;    // -log(2^-126) clamp
  const float u  = (float)k * 1.1920928955078125e-7f;   // k * 2^-23, exact
  const float l2 = __log2f(u);                          // v_log_f32
  return (double)l2 * -0.6931471805599453;
}

// ---- fused band + rowsq + d_out zeroing; K-split + f32 dots (R16 verbatim) -
__global__ __launch_bounds__(512) void band_fused_kernel(
    const float* __restrict__ H, double* __restrict__ sumsq,
    double* __restrict__ E, int* __restrict__ out, int out_n, int seq_len) {
  __shared__ __align__(16) float  tile[SROWS][KHALF];   // 64 KB
  __shared__ double ssq[SROWS];

  if (blockIdx.x == 0) {                 // fold d_out zeroing in (dispatch
    for (int t = threadIdx.x; t < out_n; t += 512) out[t] = 0;   // ordering
  }                                      // guarantees walk sees zeros)

  int wg = blockIdx.x;
  {
    const int nwg = gridDim.x;           // bijective XCD swizzle (nwg%8==0)
    if ((nwg & 7) == 0) wg = (wg & 7) * (nwg >> 3) + (wg >> 3);
  }
  const int wid  = (int)(threadIdx.x >> 6);   // 0..7
  const int lane = (int)(threadIdx.x & 63);
  const int i0   = wg * CENTERS;
  const float4* __restrict__ H4 = (const float4*)H;

  double acc[4]  = {0.0, 0.0, 0.0, 0.0};   // per staged row, across halves
  double dsum[2] = {0.0, 0.0};             // per-cc owner-lane band sums

#pragma unroll
  for (int half = 0; half < 2; ++half) {
    // ---- stage 4 rows per wave, cols [half*512, half*512+512) ----
#pragma unroll
    for (int rr = 0; rr < 4; ++rr) {
      const int local = wid * 4 + rr;    // wave-uniform
      const int row   = i0 + local;
      if (row < seq_len) {
        const float4* src = H4 + ((size_t)row << 8);
        float4* dst = (float4*)&tile[local][0];
#pragma unroll
        for (int kk = 0; kk < 2; ++kk) { // global chunk k = 2*half + kk
          float4 x = src[lane + ((half * 2 + kk) << 6)];
          dst[lane + (kk << 6)] = x;
          acc[rr] += (double)x.x * x.x + (double)x.y * x.y
                   + (double)x.z * x.z + (double)x.w * x.w;
        }
      }
    }
    if (half == 1) {                     // finalize sumsq: one butterfly
#pragma unroll
      for (int rr = 0; rr < 4; ++rr) {
        const int local = wid * 4 + rr;
        const int row   = i0 + local;
        if (row < seq_len) {
          double a = acc[rr];
#pragma unroll
          for (int off = 32; off; off >>= 1) a += __shfl_xor(a, off);
          if (lane == 0) {
            ssq[local] = a;
            if (local < CENTERS) sumsq[row] = a;  // row owned by 1 block
          }
        }
      }
    }
    __syncthreads();

    // ---- 2 centers per wave, 16 partial dots each, from LDS half ----
#pragma unroll
    for (int cc = 0; cc < 2; ++cc) {
      const int cl = wid * 2 + cc;       // 0..15, wave-uniform
      const int i  = i0 + cl;
      if (i >= seq_len) continue;

      float a[8];                        // f32: no load-time cvt
      {
        const float4* rc = (const float4*)&tile[cl][0];
#pragma unroll
        for (int kk = 0; kk < 2; ++kk) {
          float4 x = rc[lane + (kk << 6)];
          a[4*kk+0] = x.x; a[4*kk+1] = x.y; a[4*kk+2] = x.z; a[4*kk+3] = x.w;
        }
      }

      // d-loop fully unrolled; per-lane 8-term f32 partial, one cvt.
      double p[16];
#pragma unroll
      for (int d = 1; d <= 16; ++d) {
        const float4* rb = (const float4*)&tile[cl + d][0];
        float ps = 0.0f;
#pragma unroll
        for (int kk = 0; kk < 2; ++kk) {
          float4 x = rb[lane + (kk << 6)];
          ps += a[4*kk+0] * x.x + a[4*kk+1] * x.y
              + a[4*kk+2] * x.z + a[4*kk+3] * x.w;
        }
        p[d-1] = (double)ps;
      }

      // multi-value reduce-scatter: value bit3..0 <- lane bit5..2 (f64)
#pragma unroll
      for (int v = 0; v < 8; ++v) {                     // stage xor 32
        double send = (lane & 32) ? p[v] : p[v+8];
        double recv = __shfl_xor(send, 32);
        double mine = (lane & 32) ? p[v+8] : p[v];
        p[v] = mine + recv;
      }
#pragma unroll
      for (int v = 0; v < 4; ++v) {                     // stage xor 16
        double send = (lane & 16) ? p[v] : p[v+4];
        double recv = __shfl_xor(send, 16);
        double mine = (lane & 16) ? p[v+4] : p[v];
        p[v] = mine + recv;
      }
#pragma unroll
      for (int v = 0; v < 2; ++v) {                     // stage xor 8
        double send = (lane & 8) ? p[v] : p[v+2];
        double recv = __shfl_xor(send, 8);
        double mine = (lane & 8) ? p[v+2] : p[v];
        p[v] = mine + recv;
      }
      {                                                 // stage xor 4
        double send = (lane & 4) ? p[0] : p[1];
        double recv = __shfl_xor(send, 4);
        double mine = (lane & 4) ? p[1] : p[0];
        p[0] = mine + recv;
      }
      p[0] += __shfl_xor(p[0], 2);                      // stage xor 2
      p[0] += __shfl_xor(p[0], 1);                      // stage xor 1

      dsum[cc] += p[0];                  // owner-lane: half-sum accumulate
    }
    __syncthreads();                     // compute done before re-stage
  }

  // ---- epilogue: lane owns d = v+1 for its cc centers ----
  const int v = ((lane >> 2) & 1) | (((lane >> 3) & 1) << 1)
              | (((lane >> 4) & 1) << 2) | (((lane >> 5) & 1) << 3);
  const int d = v + 1;
#pragma unroll
  for (int cc = 0; cc < 2; ++cc) {
    const int cl = wid * 2 + cc;
    const int i  = i0 + cl;
    if (i < seq_len && (lane & 3) == 0 && i + d < seq_len) {
      const double ni = sqrt(ssq[cl]) + 1e-8;
      const double s  = dsum[cc] / (ni * (sqrt(ssq[cl + d]) + 1e-8));
      const double Ev = exp(5.0 * s);
      E[(size_t)i * 33 + 16 + d]       = Ev;
      E[(size_t)(i + d) * 33 + 16 - d] = Ev;
    }
  }
}

// ---- per-row sum of squares (f64) + d_out zeroing (fallback tier only) -----
__global__ __launch_bounds__(256) void rowsq_kernel(
    const float* __restrict__ H, double* __restrict__ sumsq,
    int* __restrict__ out, int out_n, int seq_len) {
  if (blockIdx.x == 0) {
    for (int t = threadIdx.x; t < out_n; t += 256) out[t] = 0;
  }
  const int row  = (int)((blockIdx.x * blockDim.x + threadIdx.x) >> 6);
  const int lane = threadIdx.x & 63;
  if (row >= seq_len) return;
  const float4* r = (const float4*)(H + (size_t)row * HID);
  double acc = 0.0;
#pragma unroll
  for (int k = 0; k < 4; ++k) {
    float4 x = r[lane + (k << 6)];
    acc += (double)x.x * x.x + (double)x.y * x.y
         + (double)x.z * x.z + (double)x.w * x.w;
  }
#pragma unroll
  for (int off = 32; off; off >>= 1) acc += __shfl_xor(acc, off);
  if (lane == 0) sumsq[row] = acc;
}

// ---- walk kernel: R13 prologue + f32 argmax value path ---------------------
__global__ __launch_bounds__(256) void walk_pre_kernel(
    const double* __restrict__ E, const double* __restrict__ sumsq,
    const int* __restrict__ viol, int* __restrict__ out,
    int nv, int seq_len) {
  int wave = (int)((blockIdx.x * blockDim.x + threadIdx.x) >> 6);
  const int lane = threadIdx.x & 63;
  if (wave >= nv * NUM_WALKS) return;
  wave = __builtin_amdgcn_readfirstlane(wave);
  const int v     = wave / NUM_WALKS;
  const int start = viol[v];

  uint32_t key0 = 0u, key1 = (uint32_t)wave;
  tf2x32(0u, 42u, key0, key1);
  key0 = __builtin_amdgcn_readfirstlane(key0);
  key1 = __builtin_amdgcn_readfirstlane(key1);

  // ---- key chain (wave-uniform SALU, saved for cold paths) ----
  uint32_t k0s[WALK_LEN], k1s[WALK_LEN];
#pragma unroll
  for (int s = 0; s < WALK_LEN; ++s) {
    k0s[s] = key0; k1s[s] = key1;
    uint32_t nk0 = 0u, nk1 = 0u; tf2x32(key0, key1, nk0, nk1);
    key0 = __builtin_amdgcn_readfirstlane(nk0);
    key1 = __builtin_amdgcn_readfirstlane(nk1);
  }

  // ---- STEP-PAIRED prologue: 4 per-lane folds produce all 8 steps' w ----
  // invw stored f32 (pick-value domain; see precision note in header).
  const int  sl_mine = lane & 31;
  const uint32_t jpk = (uint32_t)(sl_mine + (sl_mine > 15 ? 1 : 0));
  float invwp[WALK_LEN / 2];
#pragma unroll
  for (int t = 0; t < WALK_LEN / 2; ++t) {
    uint32_t ksA0 = 0u, ksA1 = 1u; tf2x32(k0s[2*t],   k1s[2*t],   ksA0, ksA1);
    uint32_t sA0  = 0u, sA1  = 0u; tf2x32(ksA0, ksA1, sA0, sA1);   // at=0
    uint32_t ksB0 = 0u, ksB1 = 1u; tf2x32(k0s[2*t+1], k1s[2*t+1], ksB0, ksB1);
    uint32_t sB0  = 0u, sB1  = 0u; tf2x32(ksB0, ksB1, sB0, sB1);   // at=0
    const uint32_t s0 = (lane & 32) ? sB0 : sA0;   // 2-op per-lane select
    const uint32_t s1 = (lane & 32) ? sB1 : sA1;
    const uint32_t bits = tf_fold(s0, s1, 0u, jpk);
    invwp[t] = (float)(1.0 / fast_neg_log(bits));
  }

  // consuming lane j reads slot sl = j - (j>16) from half (step&1)
  const int sl_use = (lane < 33 && lane != HALF_WIN)
                   ? (lane - (lane > HALF_WIN)) : 0;

  int    cur = start, prev = start, plen = 1;
  double minE = 1e300;
  bool   detected = false;
  int    aborts = 0, restarts = 0;
  // carried |h|^2 of prev / cur (identical doubles to sumsq[] entries)
  double na_d = sumsq[start], nb_d = na_d;

#pragma unroll
  for (int step = 0; step < WALK_LEN; ++step) {
    const int  myidx   = cur - HALF_WIN + lane;
    const bool myvalid = (lane < 33) && (lane != HALF_WIN) &&
                         (myidx >= 0) && (myidx < seq_len);
    const int  clipped = myidx < 0 ? 0 : (myidx >= seq_len ? seq_len - 1 : myidx);
    const double Ej = E[(size_t)cur * 33 + (lane < 33 ? lane : 0)];
    const double sq_win = sumsq[clipped];   // window |h|^2, issued with Ej
    const float  Ejf = (float)Ej;
    // my step's 1/w: one b32 bpermute from the paired prologue value
    const float invw_s = __shfl(invwp[step >> 1],
                                ((step & 1) << 5) + sl_use);

    bool found = false; int fails = 0, p = 0, cand = 0;
    double nc_d = 0.0;
    for (int at = 0; at < 3; ++at) {
      float f; int bi;
      if (myvalid) {
        if (at == 0) {
          f = Ejf * invw_s;     // hot path: 1 f32 mul
        } else {                // cold path (rare): recompute from saved key
          uint32_t ks0 = 0u, ks1 = 1u; tf2x32(k0s[step], k1s[step], ks0, ks1);
          uint32_t s0 = 0u, s1 = (uint32_t)at; tf2x32(ks0, ks1, s0, s1);
          const uint32_t bits = tf_fold(s0, s1, 0u, (uint32_t)lane);
          f = (float)(Ej / fast_neg_log(bits));
        }
        bi = lane;
      } else { f = -1.0f; bi = 1000; }
      // f32 argmax butterfly: b32 shuffles, f32 compares
#pragma unroll
      for (int off = 32; off; off >>= 1) {
        const float of = __shfl_xor(f, off);
        const int   oi = __shfl_xor(bi, off);
        if (of > f || (of == f && oi < bi)) { f = of; bi = oi; }
      }
      p    = bi;
      cand = cur - HALF_WIN + p;
      nc_d = __shfl(sq_win, p);     // == sumsq[cand], no dependent load
      bool ok;
      if (plen < 2) ok = true;
      else {
        const float na = (float)na_d, nb = (float)nb_d, nc = (float)nc_d;
        const float tr  = (na * nb * nc) /
                          ((na + 1e-8f) * (nb + 1e-8f) * (nc + 1e-8f));
        const float dev = fabsf(tr - rintf(tr));
        ok = (dev <= 0.1f) && (tr <= 1.5f);
      }
      if (ok) { found = true; break; }
      ++fails;
    }
    aborts += fails;

    if (found) {
      const double Ewin = __shfl(Ej, p);   // f64 threshold path unchanged
      minE = fmin(minE, Ewin);
      const bool closed = (cand == start) && (plen > 2);
      prev = cur; cur = cand; plen += 1;
      na_d = nb_d; nb_d = nc_d;
      if (closed) { if (minE < E_THRESH) detected = true; break; }
    } else {
      ++restarts;                 // rare path: restart chain from saved key
      uint32_t kr0 = 0u, kr1 = 2u; tf2x32(k0s[step], k1s[step], kr0, kr1);
      uint32_t h0 = 0u, h1 = 0u; tf2x32(kr0, kr1, h0, h1);
      uint32_t l0 = 0u, l1 = 1u; tf2x32(kr0, kr1, l0, l1);
      const uint32_t hi = tf_fold(h0, h1, 0u, 0u);
      const uint32_t lo = tf_fold(l0, l1, 0u, 0u);
      const uint32_t span = (uint32_t)nv;
      uint32_t mult = (65536u % span); mult = (mult * mult) % span;
      const uint32_t r = ((hi % span) * mult + (lo % span)) % span;
      const int node = viol[r];
      cur = node; prev = node; plen = 1;
      na_d = sumsq[node]; nb_d = na_d;
    }
  }

  if (lane == 0) {
    if (detected)      atomicOr(&out[v], 1);
    if (aborts != 0)   atomicAdd(&out[nv], aborts);
    if (restarts != 0) atomicAdd(&out[nv + 1], restarts);
  }
}

// ---- fallback: round-1 in-walk dot kernel (only if ws too small) -----------
__global__ __launch_bounds__(256) void walk_ref_kernel(
    const float* __restrict__ H, const int* __restrict__ viol,
    const double* __restrict__ sumsq, int* __restrict__ out,
    int nv, int seq_len) {
  const int wave = (int)((blockIdx.x * blockDim.x + threadIdx.x) >> 6);
  const int lane = threadIdx.x & 63;
  if (wave >= nv * NUM_WALKS) return;
  const int v     = wave / NUM_WALKS;
  const int start = viol[v];
  uint32_t key0 = 0u, key1 = (uint32_t)wave;
  tf2x32(0u, 42u, key0, key1);
  const float4* __restrict__ H4 = (const float4*)H;
  int    cur = start, prev = start, plen = 1;
  double min_sim = 1e9;
  bool   detected = false;
  int    aborts = 0, restarts = 0;
  for (int step = 0; step < WALK_LEN; ++step) {
    uint32_t nk0 = 0u, nk1 = 0u; tf2x32(key0, key1, nk0, nk1);
    uint32_t ks0 = 0u, ks1 = 1u; tf2x32(key0, key1, ks0, ks1);
    uint32_t kr0 = 0u, kr1 = 2u; tf2x32(key0, key1, kr0, kr1);
    const double ncur = sqrt(sumsq[cur]) + 1e-8;
    double a[16];
    {
      const float4* rc = H4 + ((size_t)cur << 8);
#pragma unroll
      for (int k = 0; k < 4; ++k) {
        float4 x = rc[lane + (k << 6)];
        a[4*k+0] = x.x; a[4*k+1] = x.y; a[4*k+2] = x.z; a[4*k+3] = x.w;
      }
    }
    double my_sim = 0.0;
    for (int jj = 0; jj < 33; ++jj) {
      const int idx = cur - HALF_WIN + jj;
      if (jj == HALF_WIN || idx < 0 || idx >= seq_len) continue;
      const float4* rb = H4 + ((size_t)idx << 8);
      double acc = 0.0;
#pragma unroll
      for (int k = 0; k < 4; ++k) {
        float4 x = rb[lane + (k << 6)];
        acc += a[4*k+0] * (double)x.x + a[4*k+1] * (double)x.y
             + a[4*k+2] * (double)x.z + a[4*k+3] * (double)x.w;
      }
#pragma unroll
      for (int off = 32; off; off >>= 1) acc += __shfl_xor(acc, off);
      const double s = acc / (ncur * (sqrt(sumsq[idx]) + 1e-8));
      if (lane == jj) my_sim = s;
    }
    bool found = false; int fails = 0, p = 0, cand = 0;
    const int  myidx   = cur - HALF_WIN + lane;
    const bool myvalid = (lane < 33) && (lane != HALF_WIN) &&
                         (myidx >= 0) && (myidx < seq_len);
    for (int at = 0; at < 3; ++at) {
      uint32_t s0 = 0u, s1 = (uint32_t)at; tf2x32(ks0, ks1, s0, s1);
      double z; int bi;
      if (myvalid) {
        const uint32_t bits = tf_fold(s0, s1, 0u, (uint32_t)lane);
        const uint32_t fb   = (bits >> 9) | 0x3f800000u;
        const float    f    = __uint_as_float(fb) - 1.0f;
        const float    u    = (f > 0.0f) ? f : 1.1754943508222875e-38f;
        const double   g    = -log(-log((double)u));
        z  = g + 5.0 * my_sim;
        bi = lane;
      } else { z = -1e300; bi = 1000; }
#pragma unroll
      for (int off = 32; off; off >>= 1) {
        const double oz = __shfl_xor(z, off);
        const int    oi = __shfl_xor(bi, off);
        if (oz > z || (oz == z && oi < bi)) { z = oz; bi = oi; }
      }
      p    = bi;
      cand = cur - HALF_WIN + p;
      bool ok;
      if (plen < 2) ok = true;
      else {
        const float na = (float)sumsq[prev], nb = (float)sumsq[cur],
                    nc = (float)sumsq[cand];
        const float tr  = (na * nb * nc) /
                          ((na + 1e-8f) * (nb + 1e-8f) * (nc + 1e-8f));
        const float dev = fabsf(tr - rintf(tr));
        ok = (dev <= 0.1f) && (tr <= 1.5f);
      }
      if (ok) { found = true; break; }
      ++fails;
    }
    aborts += fails;
    if (found) {
      const double sim = __shfl(my_sim, p);
      const double nm  = fmin(min_sim, sim);
      const bool closed = (cand == start) && (plen > 2);
      prev = cur; cur = cand; plen += 1; min_sim = nm;
      if (closed) { if (nm < 0.1) detected = true; break; }
    } else {
      ++restarts;
      uint32_t h0 = 0u, h1 = 0u; tf2x32(kr0, kr1, h0, h1);
      uint32_t l0 = 0u, l1 = 1u; tf2x32(kr0, kr1, l0, l1);
      const uint32_t hi = tf_fold(h0, h1, 0u, 0u);
      const uint32_t lo = tf_fold(l0, l1, 0u, 0u);
      const uint32_t span = (uint32_t)nv;
      uint32_t mult = (65536u % span); mult = (mult * mult) % span;
      const uint32_t r = ((hi % span) * mult + (lo % span)) % span;
      const int node = viol[r];
      cur = node; prev = node; plen = 1;
    }
    key0 = nk0; key1 = nk1;
  }
  if (lane == 0) {
    if (detected)      atomicOr(&out[v], 1);
    if (aborts != 0)   atomicAdd(&out[nv], aborts);
    if (restarts != 0) atomicAdd(&out[nv + 1], restarts);
  }
}

extern "C" void kernel_launch(void* const* d_in, const int* in_sizes, int n_in,
                              void* d_out, int out_size, void* d_ws, size_t ws_size,
                              hipStream_t stream) {
  const float* H    = (const float*)d_in[0];
  const int*   viol = (const int*)d_in[1];
  const int    nv      = in_sizes[1];
  const int    seq_len = in_sizes[0] / HID;
  const int    nwalks  = nv * NUM_WALKS;

  double* sumsq = (double*)d_ws;                       // seq_len * 8 B
  double* Etab  = (double*)((char*)d_ws + (size_t)seq_len * sizeof(double));
  const size_t need = (size_t)seq_len * sizeof(double)
                    + (size_t)seq_len * 33 * sizeof(double);

  const int wblocks = (nwalks + 3) / 4;

  if (ws_size >= need) {
    const int blocks = (seq_len + CENTERS - 1) / CENTERS;   // 512 @ 8192
    band_fused_kernel<<<blocks, 512, 0, stream>>>(H, sumsq, Etab,
                                                  (int*)d_out, out_size,
                                                  seq_len);
    walk_pre_kernel<<<wblocks, 256, 0, stream>>>(Etab, sumsq, viol,
                                                 (int*)d_out, nv, seq_len);
  } else {
    const int blocks = (seq_len + 3) / 4;
    rowsq_kernel<<<blocks, 256, 0, stream>>>(H, sumsq, (int*)d_out,
                                             out_size, seq_len);
    walk_ref_kernel<<<wblocks, 256, 0, stream>>>(H, viol, sumsq,
                                                 (int*)d_out, nv, seq_len);
  }
}

// Round 16
// 52.409 us; speedup vs baseline: 1.0961x; 1.0167x over previous
//
#include <hip/hip_runtime.h>
#include <stdint.h>
#include <math.h>

// ---------------------------------------------------------------------------
// SparseExplorerRouting, round 19.
//
// Carried facts (best = R18 53.3us; R1-R3/R5/R9-R18 PASSED absmax 0):
//   * jax_threefry_partitionable=True counter scheme; key(42) -> (0,42);
//     walk (v,w) = split child v*5+w; per-step children ctr (0,{0,1,2}).
//   * output int32 {flags[1024], sum_aborts, sum_restarts}.
//   * E-table argmax(E/w) trick, w=-log(u); minE<e^0.5 == min_sim<0.1.
//   * Walk structurally parked at R13 paired-prologue + R18 f32 pick
//     butterfly; band parked at R16 K-split + f32 partial dots.
//   * Only PIPE-RATE / LOAD-WIDTH models predict reliably (R15/R18 hit;
//     LDS-read & instruction-count models repeatedly 4-8x off).
//   * PRECISION: reference computes sims/logits/min in f32 (~1e-6 own
//     noise, proven tolerated 14x); f32 pick value proven R18; v_log_f32
//     proven R12+.
//
// Round 19 change (data width only; structure identical to R18):
//   * Ef, sumsqf tables stored f32. Walk loads 8B/lane/step (was 16B),
//     all hot-loop shuffles b32. Pick path BIT-IDENTICAL (it already
//     consumed (float)Ej); cycle check BIT-IDENTICAL (stored f32 == the
//     (float) cast used today). Only the minE<THRESH compare moves to
//     f32 (~6e-8 perturbation, inside proven ball). E table 2.2->1.1 MB.
//   * Band: epilogue stores (float)Ev; lane0 stores sumsqf=(float)acc.
//     All internal band math unchanged (f64 ssq/sumsq-order preserved).
// ---------------------------------------------------------------------------

#define HID        1024
#define NUM_WALKS  5
#define WALK_LEN   8
#define HALF_WIN   16
#define E_THRESH_F 1.6487213f           // exp(0.5) = exp(5 * BIRTH_DEATH_EPS)

#define CENTERS    16                   // centers per band block
#define SROWS      32                   // staged rows = CENTERS + 16 halo
#define KHALF      512                  // staged columns per pass

__device__ __forceinline__ void tf2x32(uint32_t k0, uint32_t k1,
                                       uint32_t& x0, uint32_t& x1) {
  uint32_t ks2 = k0 ^ k1 ^ 0x1BD11BDAu;
  x0 += k0; x1 += k1;
#define TFR(r) { x0 += x1; x1 = (x1 << (r)) | (x1 >> (32 - (r))); x1 ^= x0; }
  TFR(13) TFR(15) TFR(26) TFR(6)
  x0 += k1;  x1 += ks2 + 1u;
  TFR(17) TFR(29) TFR(16) TFR(24)
  x0 += ks2; x1 += k0 + 2u;
  TFR(13) TFR(15) TFR(26) TFR(6)
  x0 += k0;  x1 += k1 + 3u;
  TFR(17) TFR(29) TFR(16) TFR(24)
  x0 += k1;  x1 += ks2 + 4u;
  TFR(13) TFR(15) TFR(26) TFR(6)
  x0 += ks2; x1 += k0 + 5u;
#undef TFR
}

__device__ __forceinline__ uint32_t tf_fold(uint32_t k0, uint32_t k1,
                                            uint32_t c0, uint32_t c1) {
  tf2x32(k0, k1, c0, c1);
  return c0 ^ c1;
}

// w = -log(u), u = k*2^-23 (k = bits>>9), via HW v_log_f32.
// Proven safe on HW (R12-R18 absmax 0).
__device__ __forceinline__ double fast_neg_log(uint32_t bits) {
  const uint32_t k = bits >> 9;
  if (k == 0) return 87.33654475055310899;    // -log(2^-126) clamp
  const float u  = (float)k * 1.1920928955078125e-7f;   // k * 2^-23, exact
  const float l2 = __log2f(u);                          // v_log_f32
  return (double)l2 * -0.6931471805599453;
}

// ---- fused band + rowsq + d_out zeroing; K-split + f32 dots ----------------
// Internal math identical to R16/R18 band; outputs stored f32.
__global__ __launch_bounds__(512) void band_fused_kernel(
    const float* __restrict__ H, float* __restrict__ sumsqf,
    float* __restrict__ Ef, int* __restrict__ out, int out_n, int seq_len) {
  __shared__ __align__(16) float  tile[SROWS][KHALF];   // 64 KB
  __shared__ double ssq[SROWS];

  if (blockIdx.x == 0) {                 // fold d_out zeroing in (dispatch
    for (int t = threadIdx.x; t < out_n; t += 512) out[t] = 0;   // ordering
  }                                      // guarantees walk sees zeros)

  int wg = blockIdx.x;
  {
    const int nwg = gridDim.x;           // bijective XCD swizzle (nwg%8==0)
    if ((nwg & 7) == 0) wg = (wg & 7) * (nwg >> 3) + (wg >> 3);
  }
  const int wid  = (int)(threadIdx.x >> 6);   // 0..7
  const int lane = (int)(threadIdx.x & 63);
  const int i0   = wg * CENTERS;
  const float4* __restrict__ H4 = (const float4*)H;

  double acc[4]  = {0.0, 0.0, 0.0, 0.0};   // per staged row, across halves
  double dsum[2] = {0.0, 0.0};             // per-cc owner-lane band sums

#pragma unroll
  for (int half = 0; half < 2; ++half) {
    // ---- stage 4 rows per wave, cols [half*512, half*512+512) ----
#pragma unroll
    for (int rr = 0; rr < 4; ++rr) {
      const int local = wid * 4 + rr;    // wave-uniform
      const int row   = i0 + local;
      if (row < seq_len) {
        const float4* src = H4 + ((size_t)row << 8);
        float4* dst = (float4*)&tile[local][0];
#pragma unroll
        for (int kk = 0; kk < 2; ++kk) { // global chunk k = 2*half + kk
          float4 x = src[lane + ((half * 2 + kk) << 6)];
          dst[lane + (kk << 6)] = x;
          acc[rr] += (double)x.x * x.x + (double)x.y * x.y
                   + (double)x.z * x.z + (double)x.w * x.w;
        }
      }
    }
    if (half == 1) {                     // finalize sumsq: one butterfly
#pragma unroll
      for (int rr = 0; rr < 4; ++rr) {
        const int local = wid * 4 + rr;
        const int row   = i0 + local;
        if (row < seq_len) {
          double a = acc[rr];
#pragma unroll
          for (int off = 32; off; off >>= 1) a += __shfl_xor(a, off);
          if (lane == 0) {
            ssq[local] = a;
            if (local < CENTERS)
              sumsqf[row] = (float)a;    // == the (float) cast the walk's
          }                              //    cycle check used before
        }
      }
    }
    __syncthreads();

    // ---- 2 centers per wave, 16 partial dots each, from LDS half ----
#pragma unroll
    for (int cc = 0; cc < 2; ++cc) {
      const int cl = wid * 2 + cc;       // 0..15, wave-uniform
      const int i  = i0 + cl;
      if (i >= seq_len) continue;

      float a[8];                        // f32: no load-time cvt
      {
        const float4* rc = (const float4*)&tile[cl][0];
#pragma unroll
        for (int kk = 0; kk < 2; ++kk) {
          float4 x = rc[lane + (kk << 6)];
          a[4*kk+0] = x.x; a[4*kk+1] = x.y; a[4*kk+2] = x.z; a[4*kk+3] = x.w;
        }
      }

      // d-loop fully unrolled; per-lane 8-term f32 partial, one cvt.
      double p[16];
#pragma unroll
      for (int d = 1; d <= 16; ++d) {
        const float4* rb = (const float4*)&tile[cl + d][0];
        float ps = 0.0f;
#pragma unroll
        for (int kk = 0; kk < 2; ++kk) {
          float4 x = rb[lane + (kk << 6)];
          ps += a[4*kk+0] * x.x + a[4*kk+1] * x.y
              + a[4*kk+2] * x.z + a[4*kk+3] * x.w;
        }
        p[d-1] = (double)ps;
      }

      // multi-value reduce-scatter: value bit3..0 <- lane bit5..2 (f64)
#pragma unroll
      for (int v = 0; v < 8; ++v) {                     // stage xor 32
        double send = (lane & 32) ? p[v] : p[v+8];
        double recv = __shfl_xor(send, 32);
        double mine = (lane & 32) ? p[v+8] : p[v];
        p[v] = mine + recv;
      }
#pragma unroll
      for (int v = 0; v < 4; ++v) {                     // stage xor 16
        double send = (lane & 16) ? p[v] : p[v+4];
        double recv = __shfl_xor(send, 16);
        double mine = (lane & 16) ? p[v+4] : p[v];
        p[v] = mine + recv;
      }
#pragma unroll
      for (int v = 0; v < 2; ++v) {                     // stage xor 8
        double send = (lane & 8) ? p[v] : p[v+2];
        double recv = __shfl_xor(send, 8);
        double mine = (lane & 8) ? p[v+2] : p[v];
        p[v] = mine + recv;
      }
      {                                                 // stage xor 4
        double send = (lane & 4) ? p[0] : p[1];
        double recv = __shfl_xor(send, 4);
        double mine = (lane & 4) ? p[1] : p[0];
        p[0] = mine + recv;
      }
      p[0] += __shfl_xor(p[0], 2);                      // stage xor 2
      p[0] += __shfl_xor(p[0], 1);                      // stage xor 1

      dsum[cc] += p[0];                  // owner-lane: half-sum accumulate
    }
    __syncthreads();                     // compute done before re-stage
  }

  // ---- epilogue: lane owns d = v+1 for its cc centers; store f32 ----
  const int v = ((lane >> 2) & 1) | (((lane >> 3) & 1) << 1)
              | (((lane >> 4) & 1) << 2) | (((lane >> 5) & 1) << 3);
  const int d = v + 1;
#pragma unroll
  for (int cc = 0; cc < 2; ++cc) {
    const int cl = wid * 2 + cc;
    const int i  = i0 + cl;
    if (i < seq_len && (lane & 3) == 0 && i + d < seq_len) {
      const double ni = sqrt(ssq[cl]) + 1e-8;
      const double s  = dsum[cc] / (ni * (sqrt(ssq[cl + d]) + 1e-8));
      const float  Ev = (float)exp(5.0 * s);
      Ef[(size_t)i * 33 + 16 + d]       = Ev;
      Ef[(size_t)(i + d) * 33 + 16 - d] = Ev;
    }
  }
}

// ---- per-row sum of squares (f64) + d_out zeroing (fallback tier only) -----
__global__ __launch_bounds__(256) void rowsq_kernel(
    const float* __restrict__ H, double* __restrict__ sumsq,
    int* __restrict__ out, int out_n, int seq_len) {
  if (blockIdx.x == 0) {
    for (int t = threadIdx.x; t < out_n; t += 256) out[t] = 0;
  }
  const int row  = (int)((blockIdx.x * blockDim.x + threadIdx.x) >> 6);
  const int lane = threadIdx.x & 63;
  if (row >= seq_len) return;
  const float4* r = (const float4*)(H + (size_t)row * HID);
  double acc = 0.0;
#pragma unroll
  for (int k = 0; k < 4; ++k) {
    float4 x = r[lane + (k << 6)];
    acc += (double)x.x * x.x + (double)x.y * x.y
         + (double)x.z * x.z + (double)x.w * x.w;
  }
#pragma unroll
  for (int off = 32; off; off >>= 1) acc += __shfl_xor(acc, off);
  if (lane == 0) sumsq[row] = acc;
}

// ---- walk kernel: R13 prologue + R18 f32 argmax, all-f32 data --------------
__global__ __launch_bounds__(256) void walk_pre_kernel(
    const float* __restrict__ Ef, const float* __restrict__ sumsqf,
    const int* __restrict__ viol, int* __restrict__ out,
    int nv, int seq_len) {
  int wave = (int)((blockIdx.x * blockDim.x + threadIdx.x) >> 6);
  const int lane = threadIdx.x & 63;
  if (wave >= nv * NUM_WALKS) return;
  wave = __builtin_amdgcn_readfirstlane(wave);
  const int v     = wave / NUM_WALKS;
  const int start = viol[v];

  uint32_t key0 = 0u, key1 = (uint32_t)wave;
  tf2x32(0u, 42u, key0, key1);
  key0 = __builtin_amdgcn_readfirstlane(key0);
  key1 = __builtin_amdgcn_readfirstlane(key1);

  // ---- key chain (wave-uniform SALU, saved for cold paths) ----
  uint32_t k0s[WALK_LEN], k1s[WALK_LEN];
#pragma unroll
  for (int s = 0; s < WALK_LEN; ++s) {
    k0s[s] = key0; k1s[s] = key1;
    uint32_t nk0 = 0u, nk1 = 0u; tf2x32(key0, key1, nk0, nk1);
    key0 = __builtin_amdgcn_readfirstlane(nk0);
    key1 = __builtin_amdgcn_readfirstlane(nk1);
  }

  // ---- STEP-PAIRED prologue: 4 per-lane folds produce all 8 steps' w ----
  const int  sl_mine = lane & 31;
  const uint32_t jpk = (uint32_t)(sl_mine + (sl_mine > 15 ? 1 : 0));
  float invwp[WALK_LEN / 2];
#pragma unroll
  for (int t = 0; t < WALK_LEN / 2; ++t) {
    uint32_t ksA0 = 0u, ksA1 = 1u; tf2x32(k0s[2*t],   k1s[2*t],   ksA0, ksA1);
    uint32_t sA0  = 0u, sA1  = 0u; tf2x32(ksA0, ksA1, sA0, sA1);   // at=0
    uint32_t ksB0 = 0u, ksB1 = 1u; tf2x32(k0s[2*t+1], k1s[2*t+1], ksB0, ksB1);
    uint32_t sB0  = 0u, sB1  = 0u; tf2x32(ksB0, ksB1, sB0, sB1);   // at=0
    const uint32_t s0 = (lane & 32) ? sB0 : sA0;   // 2-op per-lane select
    const uint32_t s1 = (lane & 32) ? sB1 : sA1;
    const uint32_t bits = tf_fold(s0, s1, 0u, jpk);
    invwp[t] = (float)(1.0 / fast_neg_log(bits));
  }

  // consuming lane j reads slot sl = j - (j>16) from half (step&1)
  const int sl_use = (lane < 33 && lane != HALF_WIN)
                   ? (lane - (lane > HALF_WIN)) : 0;

  int   cur = start, prev = start, plen = 1;
  float minE = 1e30f;
  bool  detected = false;
  int   aborts = 0, restarts = 0;
  // carried |h|^2 of prev / cur (stored f32 == the cast used before)
  float na_f = sumsqf[start], nb_f = na_f;

#pragma unroll
  for (int step = 0; step < WALK_LEN; ++step) {
    const int  myidx   = cur - HALF_WIN + lane;
    const bool myvalid = (lane < 33) && (lane != HALF_WIN) &&
                         (myidx >= 0) && (myidx < seq_len);
    const int  clipped = myidx < 0 ? 0 : (myidx >= seq_len ? seq_len - 1 : myidx);
    const float Ejf    = Ef[(size_t)cur * 33 + (lane < 33 ? lane : 0)];
    const float sq_win = sumsqf[clipped];   // window |h|^2 (f32), with Ejf
    // my step's 1/w: one b32 bpermute from the paired prologue value
    const float invw_s = __shfl(invwp[step >> 1],
                                ((step & 1) << 5) + sl_use);

    bool found = false; int fails = 0, p = 0, cand = 0;
    float nc_f = 0.0f;
    for (int at = 0; at < 3; ++at) {
      float f; int bi;
      if (myvalid) {
        if (at == 0) {
          f = Ejf * invw_s;     // hot path: 1 f32 mul
        } else {                // cold path (rare): recompute from saved key
          uint32_t ks0 = 0u, ks1 = 1u; tf2x32(k0s[step], k1s[step], ks0, ks1);
          uint32_t s0 = 0u, s1 = (uint32_t)at; tf2x32(ks0, ks1, s0, s1);
          const uint32_t bits = tf_fold(s0, s1, 0u, (uint32_t)lane);
          f = (float)((double)Ejf / fast_neg_log(bits));
        }
        bi = lane;
      } else { f = -1.0f; bi = 1000; }
      // f32 argmax butterfly: b32 shuffles, f32 compares
#pragma unroll
      for (int off = 32; off; off >>= 1) {
        const float of = __shfl_xor(f, off);
        const int   oi = __shfl_xor(bi, off);
        if (of > f || (of == f && oi < bi)) { f = of; bi = oi; }
      }
      p    = bi;
      cand = cur - HALF_WIN + p;
      nc_f = __shfl(sq_win, p);     // == sumsqf[cand], b32 shuffle
      bool ok;
      if (plen < 2) ok = true;
      else {
        const float na = na_f, nb = nb_f, nc = nc_f;
        const float tr  = (na * nb * nc) /
                          ((na + 1e-8f) * (nb + 1e-8f) * (nc + 1e-8f));
        const float dev = fabsf(tr - rintf(tr));
        ok = (dev <= 0.1f) && (tr <= 1.5f);
      }
      if (ok) { found = true; break; }
      ++fails;
    }
    aborts += fails;

    if (found) {
      const float Ewin = __shfl(Ejf, p);   // f32 threshold path (see header)
      minE = fminf(minE, Ewin);
      const bool closed = (cand == start) && (plen > 2);
      prev = cur; cur = cand; plen += 1;
      na_f = nb_f; nb_f = nc_f;
      if (closed) { if (minE < E_THRESH_F) detected = true; break; }
    } else {
      ++restarts;                 // rare path: restart chain from saved key
      uint32_t kr0 = 0u, kr1 = 2u; tf2x32(k0s[step], k1s[step], kr0, kr1);
      uint32_t h0 = 0u, h1 = 0u; tf2x32(kr0, kr1, h0, h1);
      uint32_t l0 = 0u, l1 = 1u; tf2x32(kr0, kr1, l0, l1);
      const uint32_t hi = tf_fold(h0, h1, 0u, 0u);
      const uint32_t lo = tf_fold(l0, l1, 0u, 0u);
      const uint32_t span = (uint32_t)nv;
      uint32_t mult = (65536u % span); mult = (mult * mult) % span;
      const uint32_t r = ((hi % span) * mult + (lo % span)) % span;
      const int node = viol[r];
      cur = node; prev = node; plen = 1;
      na_f = sumsqf[node]; nb_f = na_f;
    }
  }

  if (lane == 0) {
    if (detected)      atomicOr(&out[v], 1);
    if (aborts != 0)   atomicAdd(&out[nv], aborts);
    if (restarts != 0) atomicAdd(&out[nv + 1], restarts);
  }
}

// ---- fallback: round-1 in-walk dot kernel (only if ws too small) -----------
__global__ __launch_bounds__(256) void walk_ref_kernel(
    const float* __restrict__ H, const int* __restrict__ viol,
    const double* __restrict__ sumsq, int* __restrict__ out,
    int nv, int seq_len) {
  const int wave = (int)((blockIdx.x * blockDim.x + threadIdx.x) >> 6);
  const int lane = threadIdx.x & 63;
  if (wave >= nv * NUM_WALKS) return;
  const int v     = wave / NUM_WALKS;
  const int start = viol[v];
  uint32_t key0 = 0u, key1 = (uint32_t)wave;
  tf2x32(0u, 42u, key0, key1);
  const float4* __restrict__ H4 = (const float4*)H;
  int    cur = start, prev = start, plen = 1;
  double min_sim = 1e9;
  bool   detected = false;
  int    aborts = 0, restarts = 0;
  for (int step = 0; step < WALK_LEN; ++step) {
    uint32_t nk0 = 0u, nk1 = 0u; tf2x32(key0, key1, nk0, nk1);
    uint32_t ks0 = 0u, ks1 = 1u; tf2x32(key0, key1, ks0, ks1);
    uint32_t kr0 = 0u, kr1 = 2u; tf2x32(key0, key1, kr0, kr1);
    const double ncur = sqrt(sumsq[cur]) + 1e-8;
    double a[16];
    {
      const float4* rc = H4 + ((size_t)cur << 8);
#pragma unroll
      for (int k = 0; k < 4; ++k) {
        float4 x = rc[lane + (k << 6)];
        a[4*k+0] = x.x; a[4*k+1] = x.y; a[4*k+2] = x.z; a[4*k+3] = x.w;
      }
    }
    double my_sim = 0.0;
    for (int jj = 0; jj < 33; ++jj) {
      const int idx = cur - HALF_WIN + jj;
      if (jj == HALF_WIN || idx < 0 || idx >= seq_len) continue;
      const float4* rb = H4 + ((size_t)idx << 8);
      double acc = 0.0;
#pragma unroll
      for (int k = 0; k < 4; ++k) {
        float4 x = rb[lane + (k << 6)];
        acc += a[4*k+0] * (double)x.x + a[4*k+1] * (double)x.y
             + a[4*k+2] * (double)x.z + a[4*k+3] * (double)x.w;
      }
#pragma unroll
      for (int off = 32; off; off >>= 1) acc += __shfl_xor(acc, off);
      const double s = acc / (ncur * (sqrt(sumsq[idx]) + 1e-8));
      if (lane == jj) my_sim = s;
    }
    bool found = false; int fails = 0, p = 0, cand = 0;
    const int  myidx   = cur - HALF_WIN + lane;
    const bool myvalid = (lane < 33) && (lane != HALF_WIN) &&
                         (myidx >= 0) && (myidx < seq_len);
    for (int at = 0; at < 3; ++at) {
      uint32_t s0 = 0u, s1 = (uint32_t)at; tf2x32(ks0, ks1, s0, s1);
      double z; int bi;
      if (myvalid) {
        const uint32_t bits = tf_fold(s0, s1, 0u, (uint32_t)lane);
        const uint32_t fb   = (bits >> 9) | 0x3f800000u;
        const float    f    = __uint_as_float(fb) - 1.0f;
        const float    u    = (f > 0.0f) ? f : 1.1754943508222875e-38f;
        const double   g    = -log(-log((double)u));
        z  = g + 5.0 * my_sim;
        bi = lane;
      } else { z = -1e300; bi = 1000; }
#pragma unroll
      for (int off = 32; off; off >>= 1) {
        const double oz = __shfl_xor(z, off);
        const int    oi = __shfl_xor(bi, off);
        if (oz > z || (oz == z && oi < bi)) { z = oz; bi = oi; }
      }
      p    = bi;
      cand = cur - HALF_WIN + p;
      bool ok;
      if (plen < 2) ok = true;
      else {
        const float na = (float)sumsq[prev], nb = (float)sumsq[cur],
                    nc = (float)sumsq[cand];
        const float tr  = (na * nb * nc) /
                          ((na + 1e-8f) * (nb + 1e-8f) * (nc + 1e-8f));
        const float dev = fabsf(tr - rintf(tr));
        ok = (dev <= 0.1f) && (tr <= 1.5f);
      }
      if (ok) { found = true; break; }
      ++fails;
    }
    aborts += fails;
    if (found) {
      const double sim = __shfl(my_sim, p);
      const double nm  = fmin(min_sim, sim);
      const bool closed = (cand == start) && (plen > 2);
      prev = cur; cur = cand; plen += 1; min_sim = nm;
      if (closed) { if (nm < 0.1) detected = true; break; }
    } else {
      ++restarts;
      uint32_t h0 = 0u, h1 = 0u; tf2x32(kr0, kr1, h0, h1);
      uint32_t l0 = 0u, l1 = 1u; tf2x32(kr0, kr1, l0, l1);
      const uint32_t hi = tf_fold(h0, h1, 0u, 0u);
      const uint32_t lo = tf_fold(l0, l1, 0u, 0u);
      const uint32_t span = (uint32_t)nv;
      uint32_t mult = (65536u % span); mult = (mult * mult) % span;
      const uint32_t r = ((hi % span) * mult + (lo % span)) % span;
      const int node = viol[r];
      cur = node; prev = node; plen = 1;
    }
    key0 = nk0; key1 = nk1;
  }
  if (lane == 0) {
    if (detected)      atomicOr(&out[v], 1);
    if (aborts != 0)   atomicAdd(&out[nv], aborts);
    if (restarts != 0) atomicAdd(&out[nv + 1], restarts);
  }
}

extern "C" void kernel_launch(void* const* d_in, const int* in_sizes, int n_in,
                              void* d_out, int out_size, void* d_ws, size_t ws_size,
                              hipStream_t stream) {
  const float* H    = (const float*)d_in[0];
  const int*   viol = (const int*)d_in[1];
  const int    nv      = in_sizes[1];
  const int    seq_len = in_sizes[0] / HID;
  const int    nwalks  = nv * NUM_WALKS;

  float* sumsqf = (float*)d_ws;                        // seq_len * 4 B
  float* Etabf  = (float*)((char*)d_ws + (size_t)seq_len * sizeof(float));
  const size_t need = (size_t)seq_len * sizeof(float)
                    + (size_t)seq_len * 33 * sizeof(float);

  const int wblocks = (nwalks + 3) / 4;

  if (ws_size >= need) {
    const int blocks = (seq_len + CENTERS - 1) / CENTERS;   // 512 @ 8192
    band_fused_kernel<<<blocks, 512, 0, stream>>>(H, sumsqf, Etabf,
                                                  (int*)d_out, out_size,
                                                  seq_len);
    walk_pre_kernel<<<wblocks, 256, 0, stream>>>(Etabf, sumsqf, viol,
                                                 (int*)d_out, nv, seq_len);
  } else {
    double* sumsq = (double*)d_ws;                     // tier-3 scratch
    const int blocks = (seq_len + 3) / 4;
    rowsq_kernel<<<blocks, 256, 0, stream>>>(H, sumsq, (int*)d_out,
                                             out_size, seq_len);
    walk_ref_kernel<<<wblocks, 256, 0, stream>>>(H, viol, sumsq,
                                                 (int*)d_out, nv, seq_len);
  }
}